// Round 1
// baseline (5668.185 us; speedup 1.0000x reference)
//
#include <hip/hip_runtime.h>

#define NF 128  // all feature dims are 128

// ---------------- degree ----------------
__global__ void k_degree(const int* __restrict__ dst, float* __restrict__ deg, int E) {
    int i = blockIdx.x * blockDim.x + threadIdx.x;
    int stride = gridDim.x * blockDim.x;
    for (; i < E; i += stride) atomicAdd(&deg[dst[i]], 1.0f);
}

__global__ void k_invdeg(const float* __restrict__ deg, float* __restrict__ invdeg, int n) {
    int i = blockIdx.x * blockDim.x + threadIdx.x;
    if (i < n) invdeg[i] = 1.0f / fmaxf(deg[i], 1.0f);
}

// ---------------- edge scatter-add: accum[dst] += feat[src] ----------------
// 32 lanes per edge, float4 per lane (128 floats/row).
__global__ void k_scatter(const float* __restrict__ feat, const int* __restrict__ src,
                          const int* __restrict__ dst, float* __restrict__ accum, int E) {
    long long tid = (long long)blockIdx.x * blockDim.x + threadIdx.x;
    int lane = (int)(tid & 31);
    long long estride = ((long long)gridDim.x * blockDim.x) >> 5;
    for (long long e = tid >> 5; e < E; e += estride) {
        int s = src[e];
        int d = dst[e];
        const float4 v = *reinterpret_cast<const float4*>(feat + (size_t)s * NF + lane * 4);
        float* o = accum + (size_t)d * NF + lane * 4;
        atomicAdd(o + 0, v.x);
        atomicAdd(o + 1, v.y);
        atomicAdd(o + 2, v.z);
        atomicAdd(o + 3, v.w);
    }
}

// ---------------- fused GEMM: out = act(A1 @ W[0] + (A2*invdeg) @ W[1]) ----------------
// BM=64 rows/block, BN=128 (full width), BK=32. 256 threads.
// Thread (tx = tid&31, ty = tid>>5): computes rows [ty*8, ty*8+8) x cols [tx*4, tx*4+4).
// A staged transposed in LDS (stride 68 floats -> 16B-aligned rows, <=2-way write conflicts);
// inner-loop A reads are wave-broadcast (lanes 0-31 same addr).
template <bool RELU>
__global__ __launch_bounds__(256) void k_gemm(const float* __restrict__ A1,
                                              const float* __restrict__ A2,
                                              const float* __restrict__ invdeg,
                                              const float* __restrict__ W,  // [2][128][128]
                                              float* __restrict__ out, int nrows) {
    __shared__ __align__(16) float At[32 * 68];   // [k][row] transposed, stride 68
    __shared__ __align__(16) float Wl[32 * 128];  // [k][col]

    const int tid = threadIdx.x;
    const int tx = tid & 31;
    const int ty = tid >> 5;
    const int row0 = blockIdx.x * 64;

    float acc[8][4];
#pragma unroll
    for (int i = 0; i < 8; ++i)
#pragma unroll
        for (int j = 0; j < 4; ++j) acc[i][j] = 0.0f;

    for (int phase = 0; phase < 2; ++phase) {
        const float* __restrict__ A = phase ? A2 : A1;
        const float* __restrict__ Wp = W + phase * NF * NF;
        for (int c = 0; c < 4; ++c) {
            const int kc0 = c * 32;
            __syncthreads();  // protect LDS from previous chunk's readers
            // stage A: 64 rows x 32 k, transposed into At[k][row]
#pragma unroll
            for (int i = 0; i < 2; ++i) {
                int idx = tid + i * 256;       // 0..511
                int kq = idx & 7;              // float4 group within the 32-k chunk
                int row = idx >> 3;            // 0..63
                int grow = row0 + row;
                float4 v = make_float4(0.f, 0.f, 0.f, 0.f);
                if (grow < nrows) {
                    v = *reinterpret_cast<const float4*>(A + (size_t)grow * NF + kc0 + kq * 4);
                    if (phase) {
                        float s = invdeg[grow];
                        v.x *= s; v.y *= s; v.z *= s; v.w *= s;
                    }
                }
                At[(kq * 4 + 0) * 68 + row] = v.x;
                At[(kq * 4 + 1) * 68 + row] = v.y;
                At[(kq * 4 + 2) * 68 + row] = v.z;
                At[(kq * 4 + 3) * 68 + row] = v.w;
            }
            // stage W chunk: 32 k x 128 cols
#pragma unroll
            for (int i = 0; i < 4; ++i) {
                int idx = tid + i * 256;  // 0..1023
                int c4 = idx & 31;
                int k = idx >> 5;
                *reinterpret_cast<float4*>(&Wl[k * NF + c4 * 4]) =
                    *reinterpret_cast<const float4*>(Wp + (size_t)(kc0 + k) * NF + c4 * 4);
            }
            __syncthreads();
#pragma unroll
            for (int k = 0; k < 32; ++k) {
                float4 a0 = *reinterpret_cast<const float4*>(&At[k * 68 + ty * 8]);
                float4 a1 = *reinterpret_cast<const float4*>(&At[k * 68 + ty * 8 + 4]);
                float4 w = *reinterpret_cast<const float4*>(&Wl[k * NF + tx * 4]);
                float av[8] = {a0.x, a0.y, a0.z, a0.w, a1.x, a1.y, a1.z, a1.w};
                float wv[4] = {w.x, w.y, w.z, w.w};
#pragma unroll
                for (int i = 0; i < 8; ++i)
#pragma unroll
                    for (int j = 0; j < 4; ++j) acc[i][j] += av[i] * wv[j];
            }
        }
    }
    // epilogue
#pragma unroll
    for (int i = 0; i < 8; ++i) {
        int grow = row0 + ty * 8 + i;
        if (grow < nrows) {
            float4 v = make_float4(acc[i][0], acc[i][1], acc[i][2], acc[i][3]);
            if (RELU) {
                v.x = fmaxf(v.x, 0.f); v.y = fmaxf(v.y, 0.f);
                v.z = fmaxf(v.z, 0.f); v.w = fmaxf(v.w, 0.f);
            }
            *reinterpret_cast<float4*>(out + (size_t)grow * NF + tx * 4) = v;
        }
    }
}

extern "C" void kernel_launch(void* const* d_in, const int* in_sizes, int n_in,
                              void* d_out, int out_size, void* d_ws, size_t ws_size,
                              hipStream_t stream) {
    const float* x = (const float*)d_in[0];
    const float* W_in = (const float*)d_in[1];   // [2][128][128]
    const float* W_out = (const float*)d_in[2];  // [2][128][128]
    const int* src = (const int*)d_in[3];
    const int* dst = (const int*)d_in[4];

    const int n = in_sizes[0] / NF;  // 100000
    const int E = in_sizes[3];       // 1600000
    float* outp = (float*)d_out;

    // workspace layout: deg | invdeg | accum  (h aliases d_out)
    char* ws = (char*)d_ws;
    size_t degB = ((size_t)n * 4 + 511) & ~(size_t)511;
    float* deg = (float*)ws;
    float* invdeg = (float*)(ws + degB);
    float* accum = (float*)(ws + 2 * degB);
    float* h = outp;  // layer-0 output lives in d_out; final GEMM overwrites row-locally

    hipMemsetAsync(deg, 0, (size_t)n * 4, stream);
    hipMemsetAsync(accum, 0, (size_t)n * NF * 4, stream);
    k_degree<<<1024, 256, 0, stream>>>(dst, deg, E);
    k_invdeg<<<(n + 255) / 256, 256, 0, stream>>>(deg, invdeg, n);

    // layer 0
    k_scatter<<<8192, 256, 0, stream>>>(x, src, dst, accum, E);
    k_gemm<true><<<(n + 63) / 64, 256, 0, stream>>>(x, accum, invdeg, W_in, h, n);

    // layer 1
    hipMemsetAsync(accum, 0, (size_t)n * NF * 4, stream);
    k_scatter<<<8192, 256, 0, stream>>>(h, src, dst, accum, E);
    k_gemm<false><<<(n + 63) / 64, 256, 0, stream>>>(h, accum, invdeg, W_out, outp, n);
}

// Round 2
// 649.855 us; speedup vs baseline: 8.7222x; 8.7222x over previous
//
#include <hip/hip_runtime.h>

#define NF 128  // all feature dims are 128

// ================= CSR build (counting sort by dst) =================

__global__ void k_hist(const int* __restrict__ dst, int* __restrict__ cnt, int E) {
    int i = blockIdx.x * blockDim.x + threadIdx.x;
    int stride = gridDim.x * blockDim.x;
    for (; i < E; i += stride) atomicAdd(&cnt[dst[i]], 1);
}

// pass 1: per-block (1024 elems) reduce
__global__ void k_scan1(const int* __restrict__ cnt, int* __restrict__ blocksum, int n) {
    __shared__ int sh[256];
    int b = blockIdx.x, t = threadIdx.x;
    int base = b * 1024 + t * 4;
    int s = 0;
#pragma unroll
    for (int j = 0; j < 4; ++j) {
        int idx = base + j;
        if (idx < n) s += cnt[idx];
    }
    sh[t] = s;
    __syncthreads();
    for (int off = 128; off; off >>= 1) {
        if (t < off) sh[t] += sh[t + off];
        __syncthreads();
    }
    if (t == 0) blocksum[b] = sh[0];
}

// pass 2: single block exclusive-scans block sums (nb <= 128); also writes offsets[n]=E
__global__ void k_scan2(int* __restrict__ blocksum, int nb, int* __restrict__ offsets,
                        int n, int E) {
    __shared__ int sh[128];
    int t = threadIdx.x;
    int v = (t < nb) ? blocksum[t] : 0;
    sh[t] = v;
    __syncthreads();
    for (int off = 1; off < 128; off <<= 1) {
        int x = (t >= off) ? sh[t - off] : 0;
        __syncthreads();
        sh[t] += x;
        __syncthreads();
    }
    if (t < nb) blocksum[t] = sh[t] - v;  // exclusive
    if (t == 0) offsets[n] = E;
}

// pass 3: per-block exclusive scan of 1024 elems + block offset -> offsets
__global__ void k_scan3(const int* __restrict__ cnt, const int* __restrict__ blocksum,
                        int* __restrict__ offsets, int n) {
    __shared__ int sh[256];
    int b = blockIdx.x, t = threadIdx.x;
    int base = b * 1024 + t * 4;
    int v[4];
    int s = 0;
#pragma unroll
    for (int j = 0; j < 4; ++j) {
        int idx = base + j;
        v[j] = (idx < n) ? cnt[idx] : 0;
        s += v[j];
    }
    sh[t] = s;
    __syncthreads();
    for (int off = 1; off < 256; off <<= 1) {
        int x = (t >= off) ? sh[t - off] : 0;
        __syncthreads();
        sh[t] += x;
        __syncthreads();
    }
    int excl = sh[t] - s + blocksum[b];
#pragma unroll
    for (int j = 0; j < 4; ++j) {
        int idx = base + j;
        if (idx < n) offsets[idx] = excl;
        excl += v[j];
    }
}

// fill sorted edge-source list; cursor starts as a copy of offsets
__global__ void k_fill(const int* __restrict__ src, const int* __restrict__ dst,
                       int* __restrict__ cursor, int* __restrict__ esrc, int E) {
    int i = blockIdx.x * blockDim.x + threadIdx.x;
    int stride = gridDim.x * blockDim.x;
    for (; i < E; i += stride) {
        int pos = atomicAdd(&cursor[dst[i]], 1);
        esrc[pos] = src[i];
    }
}

__global__ void k_invdeg(const int* __restrict__ cnt, float* __restrict__ invdeg, int n) {
    int i = blockIdx.x * blockDim.x + threadIdx.x;
    if (i < n) invdeg[i] = 1.0f / (float)max(cnt[i], 1);
}

// ================= gather aggregation: neigh[d] = invdeg[d] * sum over in-edges x[src] ====
// one 64-lane wave per dst node; lane owns 2 columns (float2).
__global__ __launch_bounds__(256) void k_aggregate(const float* __restrict__ feat,
                                                   const int* __restrict__ esrc,
                                                   const int* __restrict__ offsets,
                                                   const float* __restrict__ invdeg,
                                                   float* __restrict__ neigh, int n) {
    int wid = (int)((blockIdx.x * (long long)blockDim.x + threadIdx.x) >> 6);
    int lane = threadIdx.x & 63;
    if (wid >= n) return;
    int beg = offsets[wid], end = offsets[wid + 1];
    float2 a0 = make_float2(0.f, 0.f), a1 = make_float2(0.f, 0.f);
    int i = beg;
    for (; i + 2 <= end; i += 2) {
        int s0 = esrc[i], s1 = esrc[i + 1];
        float2 v0 = *reinterpret_cast<const float2*>(feat + (size_t)s0 * NF + lane * 2);
        float2 v1 = *reinterpret_cast<const float2*>(feat + (size_t)s1 * NF + lane * 2);
        a0.x += v0.x; a0.y += v0.y;
        a1.x += v1.x; a1.y += v1.y;
    }
    if (i < end) {
        int s0 = esrc[i];
        float2 v0 = *reinterpret_cast<const float2*>(feat + (size_t)s0 * NF + lane * 2);
        a0.x += v0.x; a0.y += v0.y;
    }
    float sc = invdeg[wid];
    float2 o = make_float2((a0.x + a1.x) * sc, (a0.y + a1.y) * sc);
    *reinterpret_cast<float2*>(neigh + (size_t)wid * NF + lane * 2) = o;
}

// ================= fused GEMM: out = act(A1 @ W[0] + A2 @ W[1]) =================
// (A2 = neigh is already invdeg-scaled)
template <bool RELU>
__global__ __launch_bounds__(256) void k_gemm(const float* __restrict__ A1,
                                              const float* __restrict__ A2,
                                              const float* __restrict__ W,  // [2][128][128]
                                              float* __restrict__ out, int nrows) {
    __shared__ __align__(16) float At[32 * 68];   // [k][row] transposed, stride 68
    __shared__ __align__(16) float Wl[32 * 128];  // [k][col]

    const int tid = threadIdx.x;
    const int tx = tid & 31;
    const int ty = tid >> 5;
    const int row0 = blockIdx.x * 64;

    float acc[8][4];
#pragma unroll
    for (int i = 0; i < 8; ++i)
#pragma unroll
        for (int j = 0; j < 4; ++j) acc[i][j] = 0.0f;

    for (int phase = 0; phase < 2; ++phase) {
        const float* __restrict__ A = phase ? A2 : A1;
        const float* __restrict__ Wp = W + phase * NF * NF;
        for (int c = 0; c < 4; ++c) {
            const int kc0 = c * 32;
            __syncthreads();
#pragma unroll
            for (int i = 0; i < 2; ++i) {
                int idx = tid + i * 256;  // 0..511
                int kq = idx & 7;
                int row = idx >> 3;
                int grow = row0 + row;
                float4 v = make_float4(0.f, 0.f, 0.f, 0.f);
                if (grow < nrows)
                    v = *reinterpret_cast<const float4*>(A + (size_t)grow * NF + kc0 + kq * 4);
                At[(kq * 4 + 0) * 68 + row] = v.x;
                At[(kq * 4 + 1) * 68 + row] = v.y;
                At[(kq * 4 + 2) * 68 + row] = v.z;
                At[(kq * 4 + 3) * 68 + row] = v.w;
            }
#pragma unroll
            for (int i = 0; i < 4; ++i) {
                int idx = tid + i * 256;  // 0..1023
                int c4 = idx & 31;
                int k = idx >> 5;
                *reinterpret_cast<float4*>(&Wl[k * NF + c4 * 4]) =
                    *reinterpret_cast<const float4*>(Wp + (size_t)(kc0 + k) * NF + c4 * 4);
            }
            __syncthreads();
#pragma unroll
            for (int k = 0; k < 32; ++k) {
                float4 a0 = *reinterpret_cast<const float4*>(&At[k * 68 + ty * 8]);
                float4 a1 = *reinterpret_cast<const float4*>(&At[k * 68 + ty * 8 + 4]);
                float4 w = *reinterpret_cast<const float4*>(&Wl[k * NF + tx * 4]);
                float av[8] = {a0.x, a0.y, a0.z, a0.w, a1.x, a1.y, a1.z, a1.w};
                float wv[4] = {w.x, w.y, w.z, w.w};
#pragma unroll
                for (int i = 0; i < 8; ++i)
#pragma unroll
                    for (int j = 0; j < 4; ++j) acc[i][j] += av[i] * wv[j];
            }
        }
    }
#pragma unroll
    for (int i = 0; i < 8; ++i) {
        int grow = row0 + ty * 8 + i;
        if (grow < nrows) {
            float4 v = make_float4(acc[i][0], acc[i][1], acc[i][2], acc[i][3]);
            if (RELU) {
                v.x = fmaxf(v.x, 0.f); v.y = fmaxf(v.y, 0.f);
                v.z = fmaxf(v.z, 0.f); v.w = fmaxf(v.w, 0.f);
            }
            *reinterpret_cast<float4*>(out + (size_t)grow * NF + tx * 4) = v;
        }
    }
}

extern "C" void kernel_launch(void* const* d_in, const int* in_sizes, int n_in,
                              void* d_out, int out_size, void* d_ws, size_t ws_size,
                              hipStream_t stream) {
    const float* x = (const float*)d_in[0];
    const float* W_in = (const float*)d_in[1];   // [2][128][128]
    const float* W_out = (const float*)d_in[2];  // [2][128][128]
    const int* src = (const int*)d_in[3];
    const int* dst = (const int*)d_in[4];

    const int n = in_sizes[0] / NF;  // 100000
    const int E = in_sizes[3];       // 1600000
    float* outp = (float*)d_out;

    // workspace layout
    char* ws = (char*)d_ws;
    auto align512 = [](size_t v) { return (v + 511) & ~(size_t)511; };
    size_t nb4 = align512((size_t)n * 4);
    size_t nb4p = align512((size_t)(n + 1) * 4);
    int* cnt = (int*)ws;                      // n ints
    int* offsets = (int*)(ws + nb4);          // n+1 ints
    int* cursor = (int*)(ws + nb4 + nb4p);    // n ints
    float* invdeg = (float*)(ws + nb4 + nb4p + nb4);       // n floats
    int* blocksum = (int*)(ws + nb4 + nb4p + 2 * nb4);     // <=128 ints
    int* esrc = (int*)(ws + nb4 + nb4p + 2 * nb4 + 512);   // E ints
    float* neigh = (float*)(ws + nb4 + nb4p + 2 * nb4 + 512 + align512((size_t)E * 4));
    float* h = outp;  // layer-0 output lives in d_out

    const int nscan = (n + 1023) / 1024;  // 98 blocks (<=128)

    // ---- CSR build (once; reused by both layers) ----
    hipMemsetAsync(cnt, 0, (size_t)n * 4, stream);
    k_hist<<<1024, 256, 0, stream>>>(dst, cnt, E);
    k_scan1<<<nscan, 256, 0, stream>>>(cnt, blocksum, n);
    k_scan2<<<1, 128, 0, stream>>>(blocksum, nscan, offsets, n, E);
    k_scan3<<<nscan, 256, 0, stream>>>(cnt, blocksum, offsets, n);
    k_invdeg<<<(n + 255) / 256, 256, 0, stream>>>(cnt, invdeg, n);
    hipMemcpyAsync(cursor, offsets, (size_t)n * 4, hipMemcpyDeviceToDevice, stream);
    k_fill<<<1024, 256, 0, stream>>>(src, dst, cursor, esrc, E);

    const int aggBlocks = (n + 3) / 4;  // 4 waves (=4 nodes) per 256-thread block

    // ---- layer 0 ----
    k_aggregate<<<aggBlocks, 256, 0, stream>>>(x, esrc, offsets, invdeg, neigh, n);
    k_gemm<true><<<(n + 63) / 64, 256, 0, stream>>>(x, neigh, W_in, h, n);

    // ---- layer 1 ----
    k_aggregate<<<aggBlocks, 256, 0, stream>>>(h, esrc, offsets, invdeg, neigh, n);
    k_gemm<false><<<(n + 63) / 64, 256, 0, stream>>>(h, neigh, W_out, outp, n);
}

// Round 3
// 510.379 us; speedup vs baseline: 11.1058x; 1.2733x over previous
//
#include <hip/hip_runtime.h>

#define NF 128  // all feature dims are 128

typedef __attribute__((ext_vector_type(8))) short bf16x8;
typedef __attribute__((ext_vector_type(4))) float f32x4;

__device__ __forceinline__ unsigned short f2bf(float f) {
    unsigned int u = __builtin_bit_cast(unsigned int, f);
    u = (u + 0x7fffu + ((u >> 16) & 1u)) >> 16;
    return (unsigned short)u;
}
__device__ __forceinline__ float bf2f(unsigned short h) {
    unsigned int u = ((unsigned int)h) << 16;
    return __builtin_bit_cast(float, u);
}

// ================= CSR build (counting sort by dst) =================

__global__ void k_hist(const int* __restrict__ dst, int* __restrict__ cnt, int E) {
    int i = blockIdx.x * blockDim.x + threadIdx.x;
    int stride = gridDim.x * blockDim.x;
    for (; i < E; i += stride) atomicAdd(&cnt[dst[i]], 1);
}

// pass 1: per-block (1024 elems) reduce
__global__ void k_scan1(const int* __restrict__ cnt, int* __restrict__ blocksum, int n) {
    __shared__ int sh[256];
    int b = blockIdx.x, t = threadIdx.x;
    int base = b * 1024 + t * 4;
    int s = 0;
#pragma unroll
    for (int j = 0; j < 4; ++j) {
        int idx = base + j;
        if (idx < n) s += cnt[idx];
    }
    sh[t] = s;
    __syncthreads();
    for (int off = 128; off; off >>= 1) {
        if (t < off) sh[t] += sh[t + off];
        __syncthreads();
    }
    if (t == 0) blocksum[b] = sh[0];
}

// pass 2: single block exclusive-scans block sums (nb <= 128); also writes offsets[n]=E
__global__ void k_scan2(int* __restrict__ blocksum, int nb, int* __restrict__ offsets,
                        int n, int E) {
    __shared__ int sh[128];
    int t = threadIdx.x;
    int v = (t < nb) ? blocksum[t] : 0;
    sh[t] = v;
    __syncthreads();
    for (int off = 1; off < 128; off <<= 1) {
        int x = (t >= off) ? sh[t - off] : 0;
        __syncthreads();
        sh[t] += x;
        __syncthreads();
    }
    if (t < nb) blocksum[t] = sh[t] - v;  // exclusive
    if (t == 0) offsets[n] = E;
}

// pass 3: per-block exclusive scan of 1024 elems + block offset -> offsets
__global__ void k_scan3(const int* __restrict__ cnt, const int* __restrict__ blocksum,
                        int* __restrict__ offsets, int n) {
    __shared__ int sh[256];
    int b = blockIdx.x, t = threadIdx.x;
    int base = b * 1024 + t * 4;
    int v[4];
    int s = 0;
#pragma unroll
    for (int j = 0; j < 4; ++j) {
        int idx = base + j;
        v[j] = (idx < n) ? cnt[idx] : 0;
        s += v[j];
    }
    sh[t] = s;
    __syncthreads();
    for (int off = 1; off < 256; off <<= 1) {
        int x = (t >= off) ? sh[t - off] : 0;
        __syncthreads();
        sh[t] += x;
        __syncthreads();
    }
    int excl = sh[t] - s + blocksum[b];
#pragma unroll
    for (int j = 0; j < 4; ++j) {
        int idx = base + j;
        if (idx < n) offsets[idx] = excl;
        excl += v[j];
    }
}

// fill sorted edge-source list; cursor starts as a copy of offsets
__global__ void k_fill(const int* __restrict__ src, const int* __restrict__ dst,
                       int* __restrict__ cursor, int* __restrict__ esrc, int E) {
    int i = blockIdx.x * blockDim.x + threadIdx.x;
    int stride = gridDim.x * blockDim.x;
    for (; i < E; i += stride) {
        int pos = atomicAdd(&cursor[dst[i]], 1);
        __builtin_nontemporal_store(src[i], &esrc[pos]);
    }
}

__global__ void k_invdeg(const int* __restrict__ cnt, float* __restrict__ invdeg, int n) {
    int i = blockIdx.x * blockDim.x + threadIdx.x;
    if (i < n) invdeg[i] = 1.0f / (float)max(cnt[i], 1);
}

// ================= conversions =================

// fp32 -> bf16, 8 elems/thread
__global__ void k_cvt(const float* __restrict__ in, unsigned short* __restrict__ out,
                      long long n8) {
    long long i = (long long)blockIdx.x * blockDim.x + threadIdx.x;
    if (i >= n8) return;
    const float4 a = *reinterpret_cast<const float4*>(in + i * 8);
    const float4 b = *reinterpret_cast<const float4*>(in + i * 8 + 4);
    union { unsigned short s[8]; uint4 u; } o;
    o.s[0] = f2bf(a.x); o.s[1] = f2bf(a.y); o.s[2] = f2bf(a.z); o.s[3] = f2bf(a.w);
    o.s[4] = f2bf(b.x); o.s[5] = f2bf(b.y); o.s[6] = f2bf(b.z); o.s[7] = f2bf(b.w);
    *reinterpret_cast<uint4*>(out + i * 8) = o.u;
}

// Build Bt[col][k] bf16 (128 x 256): k<128 -> W[0][k][col], k>=128 -> W[1][k-128][col]
__global__ void k_buildBt(const float* __restrict__ W, unsigned short* __restrict__ Bt) {
    int idx = blockIdx.x * blockDim.x + threadIdx.x;  // 0 .. 128*256-1
    if (idx >= 128 * 256) return;
    int c = idx >> 8;
    int k = idx & 255;
    int p = k >> 7, kk = k & 127;
    Bt[idx] = f2bf(W[((size_t)p * NF + kk) * NF + c]);
}

// ================= gather aggregation =================
// neigh[d] = invdeg[d] * sum over in-edges feat[src]; one wave per node, lane owns 2 cols.
template <bool SRCBF16>
__global__ __launch_bounds__(256) void k_aggregate(const void* __restrict__ featv,
                                                   const int* __restrict__ esrc,
                                                   const int* __restrict__ offsets,
                                                   const float* __restrict__ invdeg,
                                                   unsigned short* __restrict__ neigh, int n) {
    int wid = (int)(((long long)blockIdx.x * blockDim.x + threadIdx.x) >> 6);
    int lane = threadIdx.x & 63;
    if (wid >= n) return;
    int beg = offsets[wid], end = offsets[wid + 1];
    float x0 = 0.f, y0 = 0.f, x1 = 0.f, y1 = 0.f, x2 = 0.f, y2 = 0.f, x3 = 0.f, y3 = 0.f;
    int i = beg;
    for (; i + 4 <= end; i += 4) {
        int s0 = esrc[i], s1 = esrc[i + 1], s2 = esrc[i + 2], s3 = esrc[i + 3];
        if (SRCBF16) {
            const unsigned short* f = (const unsigned short*)featv;
            unsigned int v0 = *(const unsigned int*)(f + (size_t)s0 * NF + lane * 2);
            unsigned int v1 = *(const unsigned int*)(f + (size_t)s1 * NF + lane * 2);
            unsigned int v2 = *(const unsigned int*)(f + (size_t)s2 * NF + lane * 2);
            unsigned int v3 = *(const unsigned int*)(f + (size_t)s3 * NF + lane * 2);
            x0 += bf2f((unsigned short)v0); y0 += bf2f((unsigned short)(v0 >> 16));
            x1 += bf2f((unsigned short)v1); y1 += bf2f((unsigned short)(v1 >> 16));
            x2 += bf2f((unsigned short)v2); y2 += bf2f((unsigned short)(v2 >> 16));
            x3 += bf2f((unsigned short)v3); y3 += bf2f((unsigned short)(v3 >> 16));
        } else {
            const float* f = (const float*)featv;
            float2 v0 = *(const float2*)(f + (size_t)s0 * NF + lane * 2);
            float2 v1 = *(const float2*)(f + (size_t)s1 * NF + lane * 2);
            float2 v2 = *(const float2*)(f + (size_t)s2 * NF + lane * 2);
            float2 v3 = *(const float2*)(f + (size_t)s3 * NF + lane * 2);
            x0 += v0.x; y0 += v0.y;
            x1 += v1.x; y1 += v1.y;
            x2 += v2.x; y2 += v2.y;
            x3 += v3.x; y3 += v3.y;
        }
    }
    for (; i < end; ++i) {
        int s0 = esrc[i];
        if (SRCBF16) {
            const unsigned short* f = (const unsigned short*)featv;
            unsigned int v0 = *(const unsigned int*)(f + (size_t)s0 * NF + lane * 2);
            x0 += bf2f((unsigned short)v0); y0 += bf2f((unsigned short)(v0 >> 16));
        } else {
            const float* f = (const float*)featv;
            float2 v0 = *(const float2*)(f + (size_t)s0 * NF + lane * 2);
            x0 += v0.x; y0 += v0.y;
        }
    }
    float sc = invdeg[wid];
    float lo = (x0 + x1 + x2 + x3) * sc;
    float hi = (y0 + y1 + y2 + y3) * sc;
    unsigned int o = ((unsigned int)f2bf(hi) << 16) | (unsigned int)f2bf(lo);
    *(unsigned int*)(neigh + (size_t)wid * NF + lane * 2) = o;
}

// ================= MFMA GEMM: out = act(A1 @ W[0] + A2 @ W[1]) =================
// K=256 (k<128 from A1, k>=128 from A2=neigh). Bt[col][k] bf16.
// Block: 256 threads = 4 waves; wave owns 16 rows x 128 cols.
// Frags (m91-verified layout): A: lane holds row (lane&15), k = 8*(lane>>4)+[0..8).
// D: row = 4*(lane>>4)+r, col = lane&15.
template <bool RELU, bool A1BF16, bool OUTBF16>
__global__ __launch_bounds__(256) void k_gemm_mfma(const void* __restrict__ A1v,
                                                   const unsigned short* __restrict__ A2,
                                                   const unsigned short* __restrict__ Bt,
                                                   void* __restrict__ outv, int nrows) {
    const int tid = threadIdx.x;
    const int wave = tid >> 6;
    const int lane = tid & 63;
    const int l15 = lane & 15;
    const int lk = lane >> 4;  // k-group 0..3
    const int arow = blockIdx.x * 64 + wave * 16 + l15;
    const bool rowok = arow < nrows;

    f32x4 acc[8];
#pragma unroll
    for (int t = 0; t < 8; ++t) acc[t] = (f32x4)0.0f;

    for (int kc = 0; kc < 8; ++kc) {
        bf16x8 a;
        if (rowok) {
            if (kc < 4) {
                if (A1BF16) {
                    a = *(const bf16x8*)((const unsigned short*)A1v +
                                         (size_t)arow * NF + kc * 32 + lk * 8);
                } else {
                    const float* p = (const float*)A1v + (size_t)arow * NF + kc * 32 + lk * 8;
                    float4 u = *(const float4*)p;
                    float4 v = *(const float4*)(p + 4);
                    a[0] = (short)f2bf(u.x); a[1] = (short)f2bf(u.y);
                    a[2] = (short)f2bf(u.z); a[3] = (short)f2bf(u.w);
                    a[4] = (short)f2bf(v.x); a[5] = (short)f2bf(v.y);
                    a[6] = (short)f2bf(v.z); a[7] = (short)f2bf(v.w);
                }
            } else {
                a = *(const bf16x8*)(A2 + (size_t)arow * NF + (kc - 4) * 32 + lk * 8);
            }
        } else {
            a = (bf16x8)(short)0;
        }
#pragma unroll
        for (int t = 0; t < 8; ++t) {
            bf16x8 b = *(const bf16x8*)(Bt + (size_t)(t * 16 + l15) * 256 + kc * 32 + lk * 8);
            acc[t] = __builtin_amdgcn_mfma_f32_16x16x32_bf16(a, b, acc[t], 0, 0, 0);
        }
    }

    const int orow0 = blockIdx.x * 64 + wave * 16 + lk * 4;
#pragma unroll
    for (int r = 0; r < 4; ++r) {
        int orow = orow0 + r;
        if (orow >= nrows) continue;
#pragma unroll
        for (int t = 0; t < 8; ++t) {
            float v = acc[t][r];
            if (RELU) v = fmaxf(v, 0.f);
            if (OUTBF16)
                ((unsigned short*)outv)[(size_t)orow * NF + t * 16 + l15] = f2bf(v);
            else
                ((float*)outv)[(size_t)orow * NF + t * 16 + l15] = v;
        }
    }
}

extern "C" void kernel_launch(void* const* d_in, const int* in_sizes, int n_in,
                              void* d_out, int out_size, void* d_ws, size_t ws_size,
                              hipStream_t stream) {
    const float* x = (const float*)d_in[0];
    const float* W_in = (const float*)d_in[1];   // [2][128][128]
    const float* W_out = (const float*)d_in[2];  // [2][128][128]
    const int* src = (const int*)d_in[3];
    const int* dst = (const int*)d_in[4];

    const int n = in_sizes[0] / NF;  // 100000
    const int E = in_sizes[3];       // 1600000
    float* outp = (float*)d_out;

    // workspace carve
    char* ws = (char*)d_ws;
    size_t off = 0;
    auto take = [&](size_t bytes) {
        void* p = ws + off;
        off = (off + bytes + 511) & ~(size_t)511;
        return p;
    };
    int* cnt = (int*)take((size_t)n * 4);
    int* offsets = (int*)take((size_t)(n + 1) * 4);
    int* cursor = (int*)take((size_t)n * 4);
    float* invdeg = (float*)take((size_t)n * 4);
    int* blocksum = (int*)take(512);
    unsigned short* BtIn = (unsigned short*)take(128 * 256 * 2);
    unsigned short* BtOut = (unsigned short*)take(128 * 256 * 2);
    int* esrc = (int*)take((size_t)E * 4);
    unsigned short* hb = (unsigned short*)take((size_t)n * NF * 2);
    unsigned short* neigh = (unsigned short*)take((size_t)n * NF * 2);
    bool use_xb = (ws_size >= off + (size_t)n * NF * 2);
    unsigned short* xb = use_xb ? (unsigned short*)take((size_t)n * NF * 2) : nullptr;

    const int nscan = (n + 1023) / 1024;  // <=128

    // ---- CSR build (once; reused by both layers) ----
    hipMemsetAsync(cnt, 0, (size_t)n * 4, stream);
    k_hist<<<1024, 256, 0, stream>>>(dst, cnt, E);
    k_scan1<<<nscan, 256, 0, stream>>>(cnt, blocksum, n);
    k_scan2<<<1, 128, 0, stream>>>(blocksum, nscan, offsets, n, E);
    k_scan3<<<nscan, 256, 0, stream>>>(cnt, blocksum, offsets, n);
    k_invdeg<<<(n + 255) / 256, 256, 0, stream>>>(cnt, invdeg, n);
    hipMemcpyAsync(cursor, offsets, (size_t)n * 4, hipMemcpyDeviceToDevice, stream);
    k_fill<<<1024, 256, 0, stream>>>(src, dst, cursor, esrc, E);

    // ---- weights -> Bt bf16 ----
    k_buildBt<<<128, 256, 0, stream>>>(W_in, BtIn);
    k_buildBt<<<128, 256, 0, stream>>>(W_out, BtOut);

    if (use_xb) {
        long long n8 = (long long)n * NF / 8;
        k_cvt<<<(unsigned)((n8 + 255) / 256), 256, 0, stream>>>(x, xb, n8);
    }

    const int aggBlocks = (n + 3) / 4;
    const int gemmBlocks = (n + 63) / 64;

    // ---- layer 0 ----
    if (use_xb) {
        k_aggregate<true><<<aggBlocks, 256, 0, stream>>>(xb, esrc, offsets, invdeg, neigh, n);
        k_gemm_mfma<true, true, true>
            <<<gemmBlocks, 256, 0, stream>>>(xb, neigh, BtIn, hb, n);
    } else {
        k_aggregate<false><<<aggBlocks, 256, 0, stream>>>(x, esrc, offsets, invdeg, neigh, n);
        k_gemm_mfma<true, false, true>
            <<<gemmBlocks, 256, 0, stream>>>(x, neigh, BtIn, hb, n);
    }

    // ---- layer 1 ----
    k_aggregate<true><<<aggBlocks, 256, 0, stream>>>(hb, esrc, offsets, invdeg, neigh, n);
    k_gemm_mfma<false, true, false>
        <<<gemmBlocks, 256, 0, stream>>>(hb, neigh, BtOut, outp, n);
}

// Round 4
// 316.182 us; speedup vs baseline: 17.9270x; 1.6142x over previous
//
#include <hip/hip_runtime.h>

#define NF 128
#define NBSHIFT 8        // 256 nodes per bucket
#define NBMAX 512        // padded bucket count for scans
#define CHUNK 4096       // edges per multisplit chunk

typedef __attribute__((ext_vector_type(8))) short bf16x8;
typedef __attribute__((ext_vector_type(4))) float f32x4;

__device__ __forceinline__ unsigned short f2bf(float f) {
    unsigned int u = __builtin_bit_cast(unsigned int, f);
    u = (u + 0x7fffu + ((u >> 16) & 1u)) >> 16;
    return (unsigned short)u;
}
__device__ __forceinline__ float bf2f(unsigned short h) {
    unsigned int u = ((unsigned int)h) << 16;
    return __builtin_bit_cast(float, u);
}

// ================= bucketed CSR build =================

__global__ __launch_bounds__(256) void k_bhist(const int* __restrict__ dst,
                                               int* __restrict__ gbhist, int E, int NB) {
    __shared__ int lh[NBMAX];
    int t = threadIdx.x;
    for (int k = t; k < NBMAX; k += 256) lh[k] = 0;
    __syncthreads();
    int i = blockIdx.x * blockDim.x + t;
    int stride = gridDim.x * blockDim.x;
    for (; i < E; i += stride) atomicAdd(&lh[((unsigned)dst[i]) >> NBSHIFT], 1);
    __syncthreads();
    for (int k = t; k < NB; k += 256)
        if (lh[k]) atomicAdd(&gbhist[k], lh[k]);
}

__global__ __launch_bounds__(256) void k_bscan(const int* __restrict__ gbhist,
                                               int* __restrict__ bbase, int* __restrict__ gcursor,
                                               int NB, int E, int* __restrict__ offsets, int n) {
    __shared__ int sA[NBMAX], sB[NBMAX];
    int t = threadIdx.x;
    for (int k = t; k < NBMAX; k += 256) sA[k] = (k < NB) ? gbhist[k] : 0;
    __syncthreads();
    int* pin = sA;
    int* pout = sB;
    for (int off = 1; off < NBMAX; off <<= 1) {
        for (int k = t; k < NBMAX; k += 256) pout[k] = pin[k] + (k >= off ? pin[k - off] : 0);
        __syncthreads();
        int* tmp = pin; pin = pout; pout = tmp;
    }
    for (int k = t; k < NB; k += 256) {
        int excl = pin[k] - gbhist[k];
        bbase[k] = excl;
        gcursor[k] = excl;
    }
    if (t == 0) {
        bbase[NB] = E;
        offsets[n] = E;
    }
}

// chunked multisplit: stage a 4096-edge chunk in LDS ordered by bucket, then write
// per-bucket runs to global with one cursor atomic per (bucket, chunk).
__global__ __launch_bounds__(256) void k_bucket(const int* __restrict__ src,
                                                const int* __restrict__ dst,
                                                int* __restrict__ gcursor,
                                                unsigned long long* __restrict__ gpairs, int E) {
    __shared__ int lhist[NBMAX], lbase[NBMAX], lcur[NBMAX], gb[NBMAX];
    __shared__ int sA[NBMAX], sB[NBMAX];
    __shared__ unsigned long long stage[CHUNK];
    const int t = threadIdx.x;
    const int c0 = blockIdx.x * CHUNK;
    const int cc = min(CHUNK, E - c0);

    for (int k = t; k < NBMAX; k += 256) lhist[k] = 0;
    __syncthreads();

    int ls[16], ld[16];
#pragma unroll
    for (int j = 0; j < 16; ++j) {
        int i = t + j * 256;
        ls[j] = 0; ld[j] = 0;
        if (i < cc) {
            ls[j] = src[c0 + i];
            ld[j] = dst[c0 + i];
            atomicAdd(&lhist[((unsigned)ld[j]) >> NBSHIFT], 1);
        }
    }
    __syncthreads();
    // scan lhist -> exclusive lbase
    for (int k = t; k < NBMAX; k += 256) sA[k] = lhist[k];
    __syncthreads();
    int* pin = sA;
    int* pout = sB;
    for (int off = 1; off < NBMAX; off <<= 1) {
        for (int k = t; k < NBMAX; k += 256) pout[k] = pin[k] + (k >= off ? pin[k - off] : 0);
        __syncthreads();
        int* tmp = pin; pin = pout; pout = tmp;
    }
    for (int k = t; k < NBMAX; k += 256) {
        int excl = pin[k] - lhist[k];
        lbase[k] = excl;
        lcur[k] = excl;
    }
    __syncthreads();
#pragma unroll
    for (int j = 0; j < 16; ++j) {
        int i = t + j * 256;
        if (i < cc) {
            int b = ((unsigned)ld[j]) >> NBSHIFT;
            int pos = atomicAdd(&lcur[b], 1);
            stage[pos] = ((unsigned long long)(unsigned)ld[j] << 32) | (unsigned)ls[j];
        }
    }
    __syncthreads();
    for (int k = t; k < NBMAX; k += 256) {
        int cnt = lhist[k];
        if (cnt > 0) gb[k] = atomicAdd(&gcursor[k], cnt);
    }
    __syncthreads();
    for (int idx = t; idx < cc; idx += 256) {
        unsigned long long p = stage[idx];
        int b = (int)(p >> (32 + NBSHIFT));
        gpairs[gb[b] + (idx - lbase[b])] = p;
    }
}

// per-bucket: per-node hist + scan -> offsets/invdeg, scatter esrc within bucket region
__global__ __launch_bounds__(256) void k_bsort(const unsigned long long* __restrict__ gpairs,
                                               const int* __restrict__ bbase,
                                               int* __restrict__ offsets,
                                               float* __restrict__ invdeg,
                                               int* __restrict__ esrc, int n) {
    __shared__ int lcnt[256], lcur[256], sA[256], sB[256];
    const int b = blockIdx.x;
    const int t = threadIdx.x;
    const int base = bbase[b];
    const int c = bbase[b + 1] - base;
    const int n0 = b << NBSHIFT;

    lcnt[t] = 0;
    __syncthreads();
    for (int i = t; i < c; i += 256) {
        int node = (int)((gpairs[base + i] >> 32) & 255u);
        atomicAdd(&lcnt[node], 1);
    }
    __syncthreads();
    sA[t] = lcnt[t];
    __syncthreads();
    int* pin = sA;
    int* pout = sB;
    for (int off = 1; off < 256; off <<= 1) {
        pout[t] = pin[t] + (t >= off ? pin[t - off] : 0);
        __syncthreads();
        int* tmp = pin; pin = pout; pout = tmp;
    }
    int excl = pin[t] - lcnt[t];
    lcur[t] = excl;
    int node_g = n0 + t;
    if (node_g < n) {
        offsets[node_g] = base + excl;
        invdeg[node_g] = 1.0f / (float)max(lcnt[t], 1);
    }
    __syncthreads();
    for (int i = t; i < c; i += 256) {
        unsigned long long p = gpairs[base + i];
        int node = (int)((p >> 32) & 255u);
        int pos = atomicAdd(&lcur[node], 1);
        esrc[base + pos] = (int)(unsigned)(p & 0xffffffffu);
    }
}

// ================= conversions =================

__global__ void k_cvt(const float* __restrict__ in, unsigned short* __restrict__ out,
                      long long n8) {
    long long i = (long long)blockIdx.x * blockDim.x + threadIdx.x;
    if (i >= n8) return;
    const float4 a = *reinterpret_cast<const float4*>(in + i * 8);
    const float4 b = *reinterpret_cast<const float4*>(in + i * 8 + 4);
    union { unsigned short s[8]; uint4 u; } o;
    o.s[0] = f2bf(a.x); o.s[1] = f2bf(a.y); o.s[2] = f2bf(a.z); o.s[3] = f2bf(a.w);
    o.s[4] = f2bf(b.x); o.s[5] = f2bf(b.y); o.s[6] = f2bf(b.z); o.s[7] = f2bf(b.w);
    *reinterpret_cast<uint4*>(out + i * 8) = o.u;
}

// Build Bt[col][k] bf16 (128 x 256): k<128 -> W[0][k][col], k>=128 -> W[1][k-128][col]
__global__ void k_buildBt(const float* __restrict__ W, unsigned short* __restrict__ Bt) {
    int idx = blockIdx.x * blockDim.x + threadIdx.x;
    if (idx >= 128 * 256) return;
    int c = idx >> 8;
    int k = idx & 255;
    int p = k >> 7, kk = k & 127;
    Bt[idx] = f2bf(W[((size_t)p * NF + kk) * NF + c]);
}

// ================= gather aggregation =================
template <bool SRCBF16>
__global__ __launch_bounds__(256) void k_aggregate(const void* __restrict__ featv,
                                                   const int* __restrict__ esrc,
                                                   const int* __restrict__ offsets,
                                                   const float* __restrict__ invdeg,
                                                   unsigned short* __restrict__ neigh, int n) {
    int wid = (int)(((long long)blockIdx.x * blockDim.x + threadIdx.x) >> 6);
    int lane = threadIdx.x & 63;
    if (wid >= n) return;
    int beg = offsets[wid], end = offsets[wid + 1];
    float x0 = 0.f, y0 = 0.f, x1 = 0.f, y1 = 0.f, x2 = 0.f, y2 = 0.f, x3 = 0.f, y3 = 0.f;
    int i = beg;
    for (; i + 4 <= end; i += 4) {
        int s0 = esrc[i], s1 = esrc[i + 1], s2 = esrc[i + 2], s3 = esrc[i + 3];
        if (SRCBF16) {
            const unsigned short* f = (const unsigned short*)featv;
            unsigned int v0 = *(const unsigned int*)(f + (size_t)s0 * NF + lane * 2);
            unsigned int v1 = *(const unsigned int*)(f + (size_t)s1 * NF + lane * 2);
            unsigned int v2 = *(const unsigned int*)(f + (size_t)s2 * NF + lane * 2);
            unsigned int v3 = *(const unsigned int*)(f + (size_t)s3 * NF + lane * 2);
            x0 += bf2f((unsigned short)v0); y0 += bf2f((unsigned short)(v0 >> 16));
            x1 += bf2f((unsigned short)v1); y1 += bf2f((unsigned short)(v1 >> 16));
            x2 += bf2f((unsigned short)v2); y2 += bf2f((unsigned short)(v2 >> 16));
            x3 += bf2f((unsigned short)v3); y3 += bf2f((unsigned short)(v3 >> 16));
        } else {
            const float* f = (const float*)featv;
            float2 v0 = *(const float2*)(f + (size_t)s0 * NF + lane * 2);
            float2 v1 = *(const float2*)(f + (size_t)s1 * NF + lane * 2);
            float2 v2 = *(const float2*)(f + (size_t)s2 * NF + lane * 2);
            float2 v3 = *(const float2*)(f + (size_t)s3 * NF + lane * 2);
            x0 += v0.x; y0 += v0.y;
            x1 += v1.x; y1 += v1.y;
            x2 += v2.x; y2 += v2.y;
            x3 += v3.x; y3 += v3.y;
        }
    }
    for (; i < end; ++i) {
        int s0 = esrc[i];
        if (SRCBF16) {
            const unsigned short* f = (const unsigned short*)featv;
            unsigned int v0 = *(const unsigned int*)(f + (size_t)s0 * NF + lane * 2);
            x0 += bf2f((unsigned short)v0); y0 += bf2f((unsigned short)(v0 >> 16));
        } else {
            const float* f = (const float*)featv;
            float2 v0 = *(const float2*)(f + (size_t)s0 * NF + lane * 2);
            x0 += v0.x; y0 += v0.y;
        }
    }
    float sc = invdeg[wid];
    float lo = (x0 + x1 + x2 + x3) * sc;
    float hi = (y0 + y1 + y2 + y3) * sc;
    unsigned int o = ((unsigned int)f2bf(hi) << 16) | (unsigned int)f2bf(lo);
    *(unsigned int*)(neigh + (size_t)wid * NF + lane * 2) = o;
}

// ================= MFMA GEMM: out = act(A1 @ W[0] + A2 @ W[1]) =================
// K=256 (k<128 from A1, k>=128 from A2=neigh). Bt[col][k] bf16.
// 256 threads = 4 waves; wave owns 32 rows x 128 cols (2 A-frags share each B-frag).
template <bool RELU, bool A1BF16, bool OUTBF16>
__global__ __launch_bounds__(256) void k_gemm_mfma(const void* __restrict__ A1v,
                                                   const unsigned short* __restrict__ A2,
                                                   const unsigned short* __restrict__ Bt,
                                                   void* __restrict__ outv, int nrows) {
    const int tid = threadIdx.x;
    const int wave = tid >> 6;
    const int lane = tid & 63;
    const int l15 = lane & 15;
    const int lk = lane >> 4;  // k-group 0..3
    const int rbase = blockIdx.x * 128 + wave * 32;

    f32x4 acc0[8], acc1[8];
#pragma unroll
    for (int t = 0; t < 8; ++t) { acc0[t] = (f32x4)0.0f; acc1[t] = (f32x4)0.0f; }

    const int ar0 = rbase + l15;
    const int ar1 = rbase + 16 + l15;
    const bool ok0 = ar0 < nrows;
    const bool ok1 = ar1 < nrows;

    for (int kc = 0; kc < 8; ++kc) {
        bf16x8 a0 = (bf16x8)(short)0, a1 = (bf16x8)(short)0;
        if (kc < 4) {
            if (A1BF16) {
                const unsigned short* A1 = (const unsigned short*)A1v;
                if (ok0) a0 = *(const bf16x8*)(A1 + (size_t)ar0 * NF + kc * 32 + lk * 8);
                if (ok1) a1 = *(const bf16x8*)(A1 + (size_t)ar1 * NF + kc * 32 + lk * 8);
            } else {
                const float* A1 = (const float*)A1v;
                if (ok0) {
                    const float* p = A1 + (size_t)ar0 * NF + kc * 32 + lk * 8;
                    float4 u = *(const float4*)p;
                    float4 v = *(const float4*)(p + 4);
                    a0[0] = (short)f2bf(u.x); a0[1] = (short)f2bf(u.y);
                    a0[2] = (short)f2bf(u.z); a0[3] = (short)f2bf(u.w);
                    a0[4] = (short)f2bf(v.x); a0[5] = (short)f2bf(v.y);
                    a0[6] = (short)f2bf(v.z); a0[7] = (short)f2bf(v.w);
                }
                if (ok1) {
                    const float* p = A1 + (size_t)ar1 * NF + kc * 32 + lk * 8;
                    float4 u = *(const float4*)p;
                    float4 v = *(const float4*)(p + 4);
                    a1[0] = (short)f2bf(u.x); a1[1] = (short)f2bf(u.y);
                    a1[2] = (short)f2bf(u.z); a1[3] = (short)f2bf(u.w);
                    a1[4] = (short)f2bf(v.x); a1[5] = (short)f2bf(v.y);
                    a1[6] = (short)f2bf(v.z); a1[7] = (short)f2bf(v.w);
                }
            }
        } else {
            if (ok0) a0 = *(const bf16x8*)(A2 + (size_t)ar0 * NF + (kc - 4) * 32 + lk * 8);
            if (ok1) a1 = *(const bf16x8*)(A2 + (size_t)ar1 * NF + (kc - 4) * 32 + lk * 8);
        }
#pragma unroll
        for (int t = 0; t < 8; ++t) {
            bf16x8 b = *(const bf16x8*)(Bt + (size_t)(t * 16 + l15) * 256 + kc * 32 + lk * 8);
            acc0[t] = __builtin_amdgcn_mfma_f32_16x16x32_bf16(a0, b, acc0[t], 0, 0, 0);
            acc1[t] = __builtin_amdgcn_mfma_f32_16x16x32_bf16(a1, b, acc1[t], 0, 0, 0);
        }
    }

#pragma unroll
    for (int f = 0; f < 2; ++f) {
        const int orow0 = rbase + f * 16 + lk * 4;
#pragma unroll
        for (int r = 0; r < 4; ++r) {
            int orow = orow0 + r;
            if (orow >= nrows) continue;
#pragma unroll
            for (int t = 0; t < 8; ++t) {
                float v = f ? acc1[t][r] : acc0[t][r];
                if (RELU) v = fmaxf(v, 0.f);
                if (OUTBF16)
                    ((unsigned short*)outv)[(size_t)orow * NF + t * 16 + l15] = f2bf(v);
                else
                    ((float*)outv)[(size_t)orow * NF + t * 16 + l15] = v;
            }
        }
    }
}

extern "C" void kernel_launch(void* const* d_in, const int* in_sizes, int n_in,
                              void* d_out, int out_size, void* d_ws, size_t ws_size,
                              hipStream_t stream) {
    const float* x = (const float*)d_in[0];
    const float* W_in = (const float*)d_in[1];
    const float* W_out = (const float*)d_in[2];
    const int* src = (const int*)d_in[3];
    const int* dst = (const int*)d_in[4];

    const int n = in_sizes[0] / NF;  // 100000
    const int E = in_sizes[3];       // 1600000
    float* outp = (float*)d_out;

    const int NB = (n + 255) >> NBSHIFT;            // 391
    const int nchunks = (E + CHUNK - 1) / CHUNK;    // 391

    // workspace carve
    char* ws = (char*)d_ws;
    size_t off = 0;
    auto take = [&](size_t bytes) {
        void* p = ws + off;
        off = (off + bytes + 511) & ~(size_t)511;
        return p;
    };
    int* gbhist = (int*)take((size_t)NB * 4);
    int* bbase = (int*)take((size_t)(NB + 1) * 4);
    int* gcursor = (int*)take((size_t)NB * 4);
    int* offsets = (int*)take((size_t)(n + 1) * 4);
    float* invdeg = (float*)take((size_t)n * 4);
    unsigned short* BtIn = (unsigned short*)take(128 * 256 * 2);
    unsigned short* BtOut = (unsigned short*)take(128 * 256 * 2);
    unsigned long long* gpairs = (unsigned long long*)take((size_t)E * 8);
    int* esrc = (int*)take((size_t)E * 4);
    unsigned short* hb = (unsigned short*)take((size_t)n * NF * 2);
    unsigned short* neigh = (unsigned short*)take((size_t)n * NF * 2);
    bool use_xb = (ws_size >= off + (size_t)n * NF * 2);
    unsigned short* xb = use_xb ? (unsigned short*)take((size_t)n * NF * 2) : nullptr;

    // ---- CSR build ----
    hipMemsetAsync(gbhist, 0, (size_t)NB * 4, stream);
    k_bhist<<<512, 256, 0, stream>>>(dst, gbhist, E, NB);
    k_bscan<<<1, 256, 0, stream>>>(gbhist, bbase, gcursor, NB, E, offsets, n);
    k_bucket<<<nchunks, 256, 0, stream>>>(src, dst, gcursor, gpairs, E);
    k_bsort<<<NB, 256, 0, stream>>>(gpairs, bbase, offsets, invdeg, esrc, n);

    // ---- weights -> Bt bf16 ----
    k_buildBt<<<128, 256, 0, stream>>>(W_in, BtIn);
    k_buildBt<<<128, 256, 0, stream>>>(W_out, BtOut);

    if (use_xb) {
        long long n8 = (long long)n * NF / 8;
        k_cvt<<<(unsigned)((n8 + 255) / 256), 256, 0, stream>>>(x, xb, n8);
    }

    const int aggBlocks = (n + 3) / 4;
    const int gemmBlocks = (n + 127) / 128;

    // ---- layer 0 ----
    if (use_xb) {
        k_aggregate<true><<<aggBlocks, 256, 0, stream>>>(xb, esrc, offsets, invdeg, neigh, n);
        k_gemm_mfma<true, true, true>
            <<<gemmBlocks, 256, 0, stream>>>(xb, neigh, BtIn, hb, n);
    } else {
        k_aggregate<false><<<aggBlocks, 256, 0, stream>>>(x, esrc, offsets, invdeg, neigh, n);
        k_gemm_mfma<true, false, true>
            <<<gemmBlocks, 256, 0, stream>>>(x, neigh, BtIn, hb, n);
    }

    // ---- layer 1 ----
    k_aggregate<true><<<aggBlocks, 256, 0, stream>>>(hb, esrc, offsets, invdeg, neigh, n);
    k_gemm_mfma<false, true, false>
        <<<gemmBlocks, 256, 0, stream>>>(hb, neigh, BtOut, outp, n);
}

// Round 5
// 283.266 us; speedup vs baseline: 20.0101x; 1.1162x over previous
//
#include <hip/hip_runtime.h>

#define NF 128
#define NBSHIFT 8        // 256 nodes per bucket
#define NBMAX 512        // padded bucket count for scans
#define CHUNK 4096       // edges per multisplit chunk

typedef __attribute__((ext_vector_type(8))) short bf16x8;
typedef __attribute__((ext_vector_type(4))) float f32x4;

__device__ __forceinline__ unsigned short f2bf(float f) {
    unsigned int u = __builtin_bit_cast(unsigned int, f);
    u = (u + 0x7fffu + ((u >> 16) & 1u)) >> 16;
    return (unsigned short)u;
}
__device__ __forceinline__ float bf2f(unsigned short h) {
    unsigned int u = ((unsigned int)h) << 16;
    return __builtin_bit_cast(float, u);
}
__device__ __forceinline__ float bflo(unsigned int u) {
    return __builtin_bit_cast(float, u << 16);
}
__device__ __forceinline__ float bfhi(unsigned int u) {
    return __builtin_bit_cast(float, u & 0xffff0000u);
}

// ================= bucketed CSR build =================

__global__ __launch_bounds__(256) void k_bhist(const int* __restrict__ dst,
                                               int* __restrict__ gbhist, int E, int NB) {
    __shared__ int lh[NBMAX];
    int t = threadIdx.x;
    for (int k = t; k < NBMAX; k += 256) lh[k] = 0;
    __syncthreads();
    int i = blockIdx.x * blockDim.x + t;
    int stride = gridDim.x * blockDim.x;
    for (; i < E; i += stride) atomicAdd(&lh[((unsigned)dst[i]) >> NBSHIFT], 1);
    __syncthreads();
    for (int k = t; k < NB; k += 256)
        if (lh[k]) atomicAdd(&gbhist[k], lh[k]);
}

__global__ __launch_bounds__(256) void k_bscan(const int* __restrict__ gbhist,
                                               int* __restrict__ bbase, int* __restrict__ gcursor,
                                               int NB, int E, int* __restrict__ offsets, int n) {
    __shared__ int sA[NBMAX], sB[NBMAX];
    int t = threadIdx.x;
    for (int k = t; k < NBMAX; k += 256) sA[k] = (k < NB) ? gbhist[k] : 0;
    __syncthreads();
    int* pin = sA;
    int* pout = sB;
    for (int off = 1; off < NBMAX; off <<= 1) {
        for (int k = t; k < NBMAX; k += 256) pout[k] = pin[k] + (k >= off ? pin[k - off] : 0);
        __syncthreads();
        int* tmp = pin; pin = pout; pout = tmp;
    }
    for (int k = t; k < NB; k += 256) {
        int excl = pin[k] - gbhist[k];
        bbase[k] = excl;
        gcursor[k] = excl;
    }
    if (t == 0) {
        bbase[NB] = E;
        offsets[n] = E;
    }
}

// chunked multisplit: stage a 4096-edge chunk in LDS ordered by bucket, then write
// per-bucket runs to global with one cursor atomic per (bucket, chunk).
__global__ __launch_bounds__(256) void k_bucket(const int* __restrict__ src,
                                                const int* __restrict__ dst,
                                                int* __restrict__ gcursor,
                                                unsigned long long* __restrict__ gpairs, int E) {
    __shared__ int lhist[NBMAX], lbase[NBMAX], lcur[NBMAX], gb[NBMAX];
    __shared__ int sA[NBMAX], sB[NBMAX];
    __shared__ unsigned long long stage[CHUNK];
    const int t = threadIdx.x;
    const int c0 = blockIdx.x * CHUNK;
    const int cc = min(CHUNK, E - c0);

    for (int k = t; k < NBMAX; k += 256) lhist[k] = 0;
    __syncthreads();

    int ls[16], ld[16];
#pragma unroll
    for (int j = 0; j < 16; ++j) {
        int i = t + j * 256;
        ls[j] = 0; ld[j] = 0;
        if (i < cc) {
            ls[j] = src[c0 + i];
            ld[j] = dst[c0 + i];
            atomicAdd(&lhist[((unsigned)ld[j]) >> NBSHIFT], 1);
        }
    }
    __syncthreads();
    for (int k = t; k < NBMAX; k += 256) sA[k] = lhist[k];
    __syncthreads();
    int* pin = sA;
    int* pout = sB;
    for (int off = 1; off < NBMAX; off <<= 1) {
        for (int k = t; k < NBMAX; k += 256) pout[k] = pin[k] + (k >= off ? pin[k - off] : 0);
        __syncthreads();
        int* tmp = pin; pin = pout; pout = tmp;
    }
    for (int k = t; k < NBMAX; k += 256) {
        int excl = pin[k] - lhist[k];
        lbase[k] = excl;
        lcur[k] = excl;
    }
    __syncthreads();
#pragma unroll
    for (int j = 0; j < 16; ++j) {
        int i = t + j * 256;
        if (i < cc) {
            int b = ((unsigned)ld[j]) >> NBSHIFT;
            int pos = atomicAdd(&lcur[b], 1);
            stage[pos] = ((unsigned long long)(unsigned)ld[j] << 32) | (unsigned)ls[j];
        }
    }
    __syncthreads();
    for (int k = t; k < NBMAX; k += 256) {
        int cnt = lhist[k];
        if (cnt > 0) gb[k] = atomicAdd(&gcursor[k], cnt);
    }
    __syncthreads();
    for (int idx = t; idx < cc; idx += 256) {
        unsigned long long p = stage[idx];
        int b = (int)(p >> (32 + NBSHIFT));
        gpairs[gb[b] + (idx - lbase[b])] = p;
    }
}

// per-bucket: per-node hist + scan -> offsets/invdeg, scatter esrc within bucket region
__global__ __launch_bounds__(256) void k_bsort(const unsigned long long* __restrict__ gpairs,
                                               const int* __restrict__ bbase,
                                               int* __restrict__ offsets,
                                               float* __restrict__ invdeg,
                                               int* __restrict__ esrc, int n) {
    __shared__ int lcnt[256], lcur[256], sA[256], sB[256];
    const int b = blockIdx.x;
    const int t = threadIdx.x;
    const int base = bbase[b];
    const int c = bbase[b + 1] - base;
    const int n0 = b << NBSHIFT;

    lcnt[t] = 0;
    __syncthreads();
    for (int i = t; i < c; i += 256) {
        int node = (int)((gpairs[base + i] >> 32) & 255u);
        atomicAdd(&lcnt[node], 1);
    }
    __syncthreads();
    sA[t] = lcnt[t];
    __syncthreads();
    int* pin = sA;
    int* pout = sB;
    for (int off = 1; off < 256; off <<= 1) {
        pout[t] = pin[t] + (t >= off ? pin[t - off] : 0);
        __syncthreads();
        int* tmp = pin; pin = pout; pout = tmp;
    }
    int excl = pin[t] - lcnt[t];
    lcur[t] = excl;
    int node_g = n0 + t;
    if (node_g < n) {
        offsets[node_g] = base + excl;
        invdeg[node_g] = 1.0f / (float)max(lcnt[t], 1);
    }
    __syncthreads();
    for (int i = t; i < c; i += 256) {
        unsigned long long p = gpairs[base + i];
        int node = (int)((p >> 32) & 255u);
        int pos = atomicAdd(&lcur[node], 1);
        esrc[base + pos] = (int)(unsigned)(p & 0xffffffffu);
    }
}

// ================= conversions =================

__global__ void k_cvt(const float* __restrict__ in, unsigned short* __restrict__ out,
                      long long n8) {
    long long i = (long long)blockIdx.x * blockDim.x + threadIdx.x;
    if (i >= n8) return;
    const float4 a = *reinterpret_cast<const float4*>(in + i * 8);
    const float4 b = *reinterpret_cast<const float4*>(in + i * 8 + 4);
    union { unsigned short s[8]; uint4 u; } o;
    o.s[0] = f2bf(a.x); o.s[1] = f2bf(a.y); o.s[2] = f2bf(a.z); o.s[3] = f2bf(a.w);
    o.s[4] = f2bf(b.x); o.s[5] = f2bf(b.y); o.s[6] = f2bf(b.z); o.s[7] = f2bf(b.w);
    *reinterpret_cast<uint4*>(out + i * 8) = o.u;
}

// Build both Bt[col][k] bf16 (128 x 256) tables in one launch:
// blockIdx.x < 128 -> BtIn from W_in, else BtOut from W_out.
__global__ void k_buildBt(const float* __restrict__ Win, const float* __restrict__ Wout,
                          unsigned short* __restrict__ BtIn, unsigned short* __restrict__ BtOut) {
    int bb = blockIdx.x;
    const float* W = (bb < 128) ? Win : Wout;
    unsigned short* Bt = (bb < 128) ? BtIn : BtOut;
    int idx = (bb & 127) * 256 + threadIdx.x;
    int c = idx >> 8;
    int k = idx & 255;
    int p = k >> 7, kk = k & 127;
    Bt[idx] = f2bf(W[((size_t)p * NF + kk) * NF + c]);
}

// ================= gather aggregation (fast bf16 path) =================
// one wave per dst node; 2 edges per load instruction (half-wave each, 4 bf16/lane).
// wid forced wave-uniform (readfirstlane) -> esrc/offsets/invdeg loads go scalar.
__global__ __launch_bounds__(256) void k_agg_bf16(const unsigned short* __restrict__ feat,
                                                  const int* __restrict__ esrc,
                                                  const int* __restrict__ offsets,
                                                  const float* __restrict__ invdeg,
                                                  unsigned short* __restrict__ neigh, int n) {
    int wid0 = (int)(((long long)blockIdx.x * blockDim.x + threadIdx.x) >> 6);
    const int wid = __builtin_amdgcn_readfirstlane(wid0);
    if (wid >= n) return;
    const int lane = threadIdx.x & 63;
    const int h = lane >> 5;        // half-wave: which edge of the pair
    const int q = lane & 31;        // column group: bytes [q*8, q*8+8) = cols 4q..4q+3
    const unsigned qoff = (unsigned)q * 8u;
    const char* fb = (const char*)feat;

    const int beg = offsets[wid];
    const int end = offsets[wid + 1];
    float4 acc = make_float4(0.f, 0.f, 0.f, 0.f);

    int i = beg;
    for (; i + 8 <= end; i += 8) {
        int e0 = esrc[i + 0], e1 = esrc[i + 1], e2 = esrc[i + 2], e3 = esrc[i + 3];
        int e4 = esrc[i + 4], e5 = esrc[i + 5], e6 = esrc[i + 6], e7 = esrc[i + 7];
        unsigned o0 = (unsigned)(h ? e1 : e0) * 256u + qoff;
        unsigned o1 = (unsigned)(h ? e3 : e2) * 256u + qoff;
        unsigned o2 = (unsigned)(h ? e5 : e4) * 256u + qoff;
        unsigned o3 = (unsigned)(h ? e7 : e6) * 256u + qoff;
        uint2 v0 = *(const uint2*)(fb + o0);
        uint2 v1 = *(const uint2*)(fb + o1);
        uint2 v2 = *(const uint2*)(fb + o2);
        uint2 v3 = *(const uint2*)(fb + o3);
        acc.x += bflo(v0.x); acc.y += bfhi(v0.x); acc.z += bflo(v0.y); acc.w += bfhi(v0.y);
        acc.x += bflo(v1.x); acc.y += bfhi(v1.x); acc.z += bflo(v1.y); acc.w += bfhi(v1.y);
        acc.x += bflo(v2.x); acc.y += bfhi(v2.x); acc.z += bflo(v2.y); acc.w += bfhi(v2.y);
        acc.x += bflo(v3.x); acc.y += bfhi(v3.x); acc.z += bflo(v3.y); acc.w += bfhi(v3.y);
    }
    for (; i + 2 <= end; i += 2) {
        int e0 = esrc[i], e1 = esrc[i + 1];
        unsigned o = (unsigned)(h ? e1 : e0) * 256u + qoff;
        uint2 v = *(const uint2*)(fb + o);
        acc.x += bflo(v.x); acc.y += bfhi(v.x); acc.z += bflo(v.y); acc.w += bfhi(v.y);
    }
    if (i < end) {
        int e0 = esrc[i];
        if (h == 0) {
            unsigned o = (unsigned)e0 * 256u + qoff;
            uint2 v = *(const uint2*)(fb + o);
            acc.x += bflo(v.x); acc.y += bfhi(v.x); acc.z += bflo(v.y); acc.w += bfhi(v.y);
        }
    }
    // combine the two half-waves (both end up holding the full sums)
    acc.x += __shfl_xor(acc.x, 32);
    acc.y += __shfl_xor(acc.y, 32);
    acc.z += __shfl_xor(acc.z, 32);
    acc.w += __shfl_xor(acc.w, 32);

    const float sc = invdeg[wid];
    float ca = (h ? acc.z : acc.x) * sc;   // even column of this lane's output dword
    float cb = (h ? acc.w : acc.y) * sc;   // odd column
    unsigned pk;
    asm("v_cvt_pk_bf16_f32 %0, %1, %2" : "=v"(pk) : "v"(ca), "v"(cb));
    // lane (h,q) writes output dword index 2q+h -> cols 4q+2h, 4q+2h+1
    *(unsigned*)((char*)neigh + (size_t)wid * 256 + (unsigned)(2 * q + h) * 4u) = pk;
}

// fallback fp32-source aggregate (only used if ws too small for xb)
__global__ __launch_bounds__(256) void k_agg_f32(const float* __restrict__ feat,
                                                 const int* __restrict__ esrc,
                                                 const int* __restrict__ offsets,
                                                 const float* __restrict__ invdeg,
                                                 unsigned short* __restrict__ neigh, int n) {
    int wid0 = (int)(((long long)blockIdx.x * blockDim.x + threadIdx.x) >> 6);
    const int wid = __builtin_amdgcn_readfirstlane(wid0);
    if (wid >= n) return;
    int lane = threadIdx.x & 63;
    int beg = offsets[wid], end = offsets[wid + 1];
    float a0 = 0.f, a1 = 0.f;
    for (int i = beg; i < end; ++i) {
        int s0 = esrc[i];
        float2 v0 = *(const float2*)(feat + (size_t)s0 * NF + lane * 2);
        a0 += v0.x; a1 += v0.y;
    }
    float sc = invdeg[wid];
    unsigned pk;
    float ca = a0 * sc, cb = a1 * sc;
    asm("v_cvt_pk_bf16_f32 %0, %1, %2" : "=v"(pk) : "v"(ca), "v"(cb));
    *(unsigned*)(neigh + (size_t)wid * NF + lane * 2) = pk;
}

// ================= MFMA GEMM: out = act(A1 @ W[0] + A2 @ W[1]) =================
// K=256 (k<128 from A1, k>=128 from A2=neigh). Bt[col][k] bf16.
// 256 threads = 4 waves; wave owns 32 rows x 128 cols (2 A-frags share each B-frag).
template <bool RELU, bool A1BF16, bool OUTBF16>
__global__ __launch_bounds__(256) void k_gemm_mfma(const void* __restrict__ A1v,
                                                   const unsigned short* __restrict__ A2,
                                                   const unsigned short* __restrict__ Bt,
                                                   void* __restrict__ outv, int nrows) {
    const int tid = threadIdx.x;
    const int wave = tid >> 6;
    const int lane = tid & 63;
    const int l15 = lane & 15;
    const int lk = lane >> 4;  // k-group 0..3
    const int rbase = blockIdx.x * 128 + wave * 32;

    f32x4 acc0[8], acc1[8];
#pragma unroll
    for (int t = 0; t < 8; ++t) { acc0[t] = (f32x4)0.0f; acc1[t] = (f32x4)0.0f; }

    const int ar0 = rbase + l15;
    const int ar1 = rbase + 16 + l15;
    const bool ok0 = ar0 < nrows;
    const bool ok1 = ar1 < nrows;

    for (int kc = 0; kc < 8; ++kc) {
        bf16x8 a0 = (bf16x8)(short)0, a1 = (bf16x8)(short)0;
        if (kc < 4) {
            if (A1BF16) {
                const unsigned short* A1 = (const unsigned short*)A1v;
                if (ok0) a0 = *(const bf16x8*)(A1 + (size_t)ar0 * NF + kc * 32 + lk * 8);
                if (ok1) a1 = *(const bf16x8*)(A1 + (size_t)ar1 * NF + kc * 32 + lk * 8);
            } else {
                const float* A1 = (const float*)A1v;
                if (ok0) {
                    const float* p = A1 + (size_t)ar0 * NF + kc * 32 + lk * 8;
                    float4 u = *(const float4*)p;
                    float4 v = *(const float4*)(p + 4);
                    a0[0] = (short)f2bf(u.x); a0[1] = (short)f2bf(u.y);
                    a0[2] = (short)f2bf(u.z); a0[3] = (short)f2bf(u.w);
                    a0[4] = (short)f2bf(v.x); a0[5] = (short)f2bf(v.y);
                    a0[6] = (short)f2bf(v.z); a0[7] = (short)f2bf(v.w);
                }
                if (ok1) {
                    const float* p = A1 + (size_t)ar1 * NF + kc * 32 + lk * 8;
                    float4 u = *(const float4*)p;
                    float4 v = *(const float4*)(p + 4);
                    a1[0] = (short)f2bf(u.x); a1[1] = (short)f2bf(u.y);
                    a1[2] = (short)f2bf(u.z); a1[3] = (short)f2bf(u.w);
                    a1[4] = (short)f2bf(v.x); a1[5] = (short)f2bf(v.y);
                    a1[6] = (short)f2bf(v.z); a1[7] = (short)f2bf(v.w);
                }
            }
        } else {
            if (ok0) a0 = *(const bf16x8*)(A2 + (size_t)ar0 * NF + (kc - 4) * 32 + lk * 8);
            if (ok1) a1 = *(const bf16x8*)(A2 + (size_t)ar1 * NF + (kc - 4) * 32 + lk * 8);
        }
#pragma unroll
        for (int t = 0; t < 8; ++t) {
            bf16x8 b = *(const bf16x8*)(Bt + (size_t)(t * 16 + l15) * 256 + kc * 32 + lk * 8);
            acc0[t] = __builtin_amdgcn_mfma_f32_16x16x32_bf16(a0, b, acc0[t], 0, 0, 0);
            acc1[t] = __builtin_amdgcn_mfma_f32_16x16x32_bf16(a1, b, acc1[t], 0, 0, 0);
        }
    }

#pragma unroll
    for (int f = 0; f < 2; ++f) {
        const int orow0 = rbase + f * 16 + lk * 4;
#pragma unroll
        for (int r = 0; r < 4; ++r) {
            int orow = orow0 + r;
            if (orow >= nrows) continue;
#pragma unroll
            for (int t = 0; t < 8; ++t) {
                float v = f ? acc1[t][r] : acc0[t][r];
                if (RELU) v = fmaxf(v, 0.f);
                if (OUTBF16)
                    ((unsigned short*)outv)[(size_t)orow * NF + t * 16 + l15] = f2bf(v);
                else
                    ((float*)outv)[(size_t)orow * NF + t * 16 + l15] = v;
            }
        }
    }
}

extern "C" void kernel_launch(void* const* d_in, const int* in_sizes, int n_in,
                              void* d_out, int out_size, void* d_ws, size_t ws_size,
                              hipStream_t stream) {
    const float* x = (const float*)d_in[0];
    const float* W_in = (const float*)d_in[1];
    const float* W_out = (const float*)d_in[2];
    const int* src = (const int*)d_in[3];
    const int* dst = (const int*)d_in[4];

    const int n = in_sizes[0] / NF;  // 100000
    const int E = in_sizes[3];       // 1600000
    float* outp = (float*)d_out;

    const int NB = (n + 255) >> NBSHIFT;
    const int nchunks = (E + CHUNK - 1) / CHUNK;

    // workspace carve
    char* ws = (char*)d_ws;
    size_t off = 0;
    auto take = [&](size_t bytes) {
        void* p = ws + off;
        off = (off + bytes + 511) & ~(size_t)511;
        return p;
    };
    int* gbhist = (int*)take((size_t)NB * 4);
    int* bbase = (int*)take((size_t)(NB + 1) * 4);
    int* gcursor = (int*)take((size_t)NB * 4);
    int* offsets = (int*)take((size_t)(n + 1) * 4);
    float* invdeg = (float*)take((size_t)n * 4);
    unsigned short* BtIn = (unsigned short*)take(128 * 256 * 2);
    unsigned short* BtOut = (unsigned short*)take(128 * 256 * 2);
    unsigned long long* gpairs = (unsigned long long*)take((size_t)E * 8);
    int* esrc = (int*)take((size_t)E * 4);
    unsigned short* hb = (unsigned short*)take((size_t)n * NF * 2);
    unsigned short* neigh = (unsigned short*)take((size_t)n * NF * 2);
    bool use_xb = (ws_size >= off + (size_t)n * NF * 2);
    unsigned short* xb = use_xb ? (unsigned short*)take((size_t)n * NF * 2) : nullptr;

    // ---- CSR build ----
    hipMemsetAsync(gbhist, 0, (size_t)NB * 4, stream);
    k_bhist<<<512, 256, 0, stream>>>(dst, gbhist, E, NB);
    k_bscan<<<1, 256, 0, stream>>>(gbhist, bbase, gcursor, NB, E, offsets, n);
    k_bucket<<<nchunks, 256, 0, stream>>>(src, dst, gcursor, gpairs, E);
    k_bsort<<<NB, 256, 0, stream>>>(gpairs, bbase, offsets, invdeg, esrc, n);

    // ---- weights -> Bt bf16 (both in one launch) ----
    k_buildBt<<<256, 256, 0, stream>>>(W_in, W_out, BtIn, BtOut);

    if (use_xb) {
        long long n8 = (long long)n * NF / 8;
        k_cvt<<<(unsigned)((n8 + 255) / 256), 256, 0, stream>>>(x, xb, n8);
    }

    const int aggBlocks = (n + 3) / 4;
    const int gemmBlocks = (n + 127) / 128;

    // ---- layer 0 ----
    if (use_xb) {
        k_agg_bf16<<<aggBlocks, 256, 0, stream>>>(xb, esrc, offsets, invdeg, neigh, n);
        k_gemm_mfma<true, true, true>
            <<<gemmBlocks, 256, 0, stream>>>(xb, neigh, BtIn, hb, n);
    } else {
        k_agg_f32<<<aggBlocks, 256, 0, stream>>>(x, esrc, offsets, invdeg, neigh, n);
        k_gemm_mfma<true, false, true>
            <<<gemmBlocks, 256, 0, stream>>>(x, neigh, BtIn, hb, n);
    }

    // ---- layer 1 ----
    k_agg_bf16<<<aggBlocks, 256, 0, stream>>>(hb, esrc, offsets, invdeg, neigh, n);
    k_gemm_mfma<false, true, false>
        <<<gemmBlocks, 256, 0, stream>>>(hb, neigh, BtOut, outp, n);
}